// Round 1
// baseline (556.050 us; speedup 1.0000x reference)
//
#include <hip/hip_runtime.h>
#include <math.h>

#define NN 512
#define XD 256
#define ED 128
#define JC 32
#define NCHUNK (NN/JC)

typedef __attribute__((ext_vector_type(8))) short s8v;
typedef __attribute__((ext_vector_type(4))) float f4v;

__device__ __forceinline__ short f2bf(float f) {
    union { float f; unsigned u; } v; v.f = f;
    unsigned r = (v.u + 0x7FFFu + ((v.u >> 16) & 1u)) >> 16;
    return (short)r;
}
__device__ __forceinline__ float bf2f(short s) {
    union { unsigned u; float f; } v;
    v.u = ((unsigned)(unsigned short)s) << 16;
    return v.f;
}
__device__ __forceinline__ s8v load8_bf(const float* __restrict__ p) {
    const float4* p4 = (const float4*)p;
    float4 a = p4[0], b = p4[1];
    s8v r;
    r[0]=f2bf(a.x); r[1]=f2bf(a.y); r[2]=f2bf(a.z); r[3]=f2bf(a.w);
    r[4]=f2bf(b.x); r[5]=f2bf(b.y); r[6]=f2bf(b.z); r[7]=f2bf(b.w);
    return r;
}

// ---------------- kernel 1: Q (pre-scaled), K, V ----------------
__global__ void qkv_kernel(const float* __restrict__ x,
                           const float* __restrict__ Wq, const float* __restrict__ bq,
                           const float* __restrict__ Wk, const float* __restrict__ bk,
                           const float* __restrict__ Wv, const float* __restrict__ bv,
                           float* __restrict__ out) {
    const int i = blockIdx.x, which = blockIdx.y, t = threadIdx.x;
    __shared__ float sx[XD];
    sx[t] = x[i*XD + t];
    __syncthreads();
    const float* W = which==0 ? Wq : (which==1 ? Wk : Wv);
    const float* b = which==0 ? bq : (which==1 ? bk : bv);
    const float4* W4 = (const float4*)(W + t*XD);
    const float4* x4 = (const float4*)sx;
    float acc = 0.f;
    #pragma unroll 8
    for (int k4 = 0; k4 < XD/4; ++k4) {
        float4 w = W4[k4]; float4 xv = x4[k4];
        acc += w.x*xv.x + w.y*xv.y + w.z*xv.z + w.w*xv.w;
    }
    acc += b[t];
    if (which == 0) acc *= 0.17677669529663688f;  // 1/sqrt(32)
    out[((size_t)which*NN + i)*XD + t] = acc;
}

// ---------------- kernel 2: fused E1/E2/Y/newE/softmax/weighted_V ----------------
#define SE_STRIDE 136   // 128 + 8 pad (bf16 units), rows 16B-aligned, conflict-free b128
#define SY_STRIDE 264   // 256 + 8 pad

__global__ __launch_bounds__(512, 2) void fused_kernel(
    const float* __restrict__ e,
    const float* __restrict__ Qs, const float* __restrict__ Km, const float* __restrict__ Vm,
    const float* __restrict__ Wem, const float* __restrict__ bem,
    const float* __restrict__ Wea, const float* __restrict__ bea,
    const float* __restrict__ Weo, const float* __restrict__ beo,
    float* __restrict__ outE, float* __restrict__ wV)
{
    __shared__ short sE[JC*SE_STRIDE];
    __shared__ short sY[JC*SY_STRIDE];
    __shared__ float sRed[3*512];

    const int i = blockIdx.x;
    const int t = threadIdx.x;
    const int wave = t >> 6;
    const int lane = t & 63;
    const int quad = (lane >> 4) & 3;
    const int l16 = lane & 15;

    // --- B fragments resident in registers for the whole block ---
    // GEMM1/2 (E1,E2): wave handles columns [wave*32, wave*32+32), 2 n-tiles
    const int wn0 = wave * 32;
    s8v B1f[2][4], B2f[2][4];
    float q_l[2], bm1[2], bea_l[2];
    #pragma unroll
    for (int nt = 0; nt < 2; ++nt) {
        const int c = wn0 + nt*16 + l16;
        q_l[nt]   = Qs[i*XD + c];
        bm1[nt]   = bem[c] + 1.0f;    // fold the (E1 + 1)
        bea_l[nt] = bea[c];
        #pragma unroll
        for (int ks = 0; ks < 4; ++ks) {
            const int kb = ks*32 + quad*8;
            B1f[nt][ks] = load8_bf(Wem + (size_t)c*ED + kb);
            B2f[nt][ks] = load8_bf(Wea + (size_t)c*ED + kb);
        }
    }
    // GEMM3 (newE): wave handles output cols [wave*16, wave*16+16)
    const int oo = wave*16 + l16;
    s8v B3f[8];
    #pragma unroll
    for (int ks = 0; ks < 8; ++ks)
        B3f[ks] = load8_bf(Weo + (size_t)oo*XD + ks*32 + quad*8);
    const float beo_l = beo[oo];

    // online-softmax state: thread t handles channel (t&255), j-half (t>>8)
    const int sc_c = t & 255;
    const int sc_jh = t >> 8;
    float m_run = -INFINITY, l_run = 0.f, a_run = 0.f;

    for (int ch = 0; ch < NCHUNK; ++ch) {
        // --- stage e chunk -> LDS bf16 ---
        {
            const int j  = t >> 4;
            const int k0 = (t & 15) * 8;
            const float* src = e + ((size_t)i*NN + (size_t)(ch*JC + j))*ED + k0;
            *(s8v*)(&sE[j*SE_STRIDE + k0]) = load8_bf(src);
        }
        __syncthreads();

        // --- GEMM1/2: E1,E2 [32 x 256] ---
        f4v acc1[2][2], acc2[2][2];
        #pragma unroll
        for (int mt = 0; mt < 2; ++mt)
            #pragma unroll
            for (int nt = 0; nt < 2; ++nt) {
                f4v z = {0.f, 0.f, 0.f, 0.f};
                acc1[mt][nt] = z; acc2[mt][nt] = z;
            }
        #pragma unroll
        for (int ks = 0; ks < 4; ++ks) {
            #pragma unroll
            for (int mt = 0; mt < 2; ++mt) {
                s8v af = *(const s8v*)(&sE[(mt*16 + l16)*SE_STRIDE + ks*32 + quad*8]);
                #pragma unroll
                for (int nt = 0; nt < 2; ++nt) {
                    acc1[mt][nt] = __builtin_amdgcn_mfma_f32_16x16x32_bf16(af, B1f[nt][ks], acc1[mt][nt], 0, 0, 0);
                    acc2[mt][nt] = __builtin_amdgcn_mfma_f32_16x16x32_bf16(af, B2f[nt][ks], acc2[mt][nt], 0, 0, 0);
                }
            }
        }

        // --- elementwise: Y = qK*(E1+1) + E2  -> sY (bf16) ---
        #pragma unroll
        for (int mt = 0; mt < 2; ++mt) {
            const int jlb = mt*16 + quad*4;
            const int jgb = ch*JC + jlb;
            #pragma unroll
            for (int nt = 0; nt < 2; ++nt) {
                const int c = wn0 + nt*16 + l16;
                #pragma unroll
                for (int r = 0; r < 4; ++r) {
                    float e1 = acc1[mt][nt][r] + bm1[nt];
                    float e2 = acc2[mt][nt][r] + bea_l[nt];
                    float kv = Km[(size_t)(jgb + r)*XD + c];
                    float y  = q_l[nt]*kv*e1 + e2;
                    sY[(jlb + r)*SY_STRIDE + c] = f2bf(y);
                }
            }
        }
        __syncthreads();

        // --- GEMM3: newE chunk [32 x 128] ---
        f4v acc3[2];
        {
            f4v z = {0.f, 0.f, 0.f, 0.f};
            acc3[0] = z; acc3[1] = z;
        }
        #pragma unroll
        for (int ks = 0; ks < 8; ++ks)
            #pragma unroll
            for (int mt = 0; mt < 2; ++mt) {
                s8v af = *(const s8v*)(&sY[(mt*16 + l16)*SY_STRIDE + ks*32 + quad*8]);
                acc3[mt] = __builtin_amdgcn_mfma_f32_16x16x32_bf16(af, B3f[ks], acc3[mt], 0, 0, 0);
            }
        #pragma unroll
        for (int mt = 0; mt < 2; ++mt) {
            const int jlb = mt*16 + quad*4;
            #pragma unroll
            for (int r = 0; r < 4; ++r) {
                const int jg = ch*JC + jlb + r;
                outE[((size_t)i*NN + jg)*ED + oo] = acc3[mt][r] + beo_l;
            }
        }

        // --- online softmax + weighted V ---
        #pragma unroll
        for (int jj = 0; jj < 16; ++jj) {
            const int jl = sc_jh*16 + jj;
            const int jg = ch*JC + jl;
            float y  = bf2f(sY[jl*SY_STRIDE + sc_c]);
            float v  = Vm[(size_t)jg*XD + sc_c];
            float mn = fmaxf(m_run, y);
            float s0 = __expf(m_run - mn);
            float p  = __expf(y - mn);
            l_run = l_run*s0 + p;
            a_run = a_run*s0 + p*v;
            m_run = mn;
        }
        __syncthreads();
    }

    // combine the two j-halves, write weighted_V
    sRed[t] = m_run; sRed[512 + t] = l_run; sRed[1024 + t] = a_run;
    __syncthreads();
    if (t < 256) {
        float m0 = sRed[t],        m1 = sRed[256 + t];
        float l0 = sRed[512 + t],  l1 = sRed[768 + t];
        float a0 = sRed[1024 + t], a1 = sRed[1280 + t];
        float M  = fmaxf(m0, m1);
        float e0 = __expf(m0 - M), e1x = __expf(m1 - M);
        float L  = l0*e0 + l1*e1x;
        float A  = a0*e0 + a1*e1x;
        wV[(size_t)i*XD + t] = A / L;
    }
}

// ---------------- kernel 3: newX = weighted_V @ Wxo^T + bxo ----------------
__global__ void newx_kernel(const float* __restrict__ wV,
                            const float* __restrict__ Wxo, const float* __restrict__ bxo,
                            float* __restrict__ outX) {
    const int i = blockIdx.x, t = threadIdx.x;
    __shared__ float sv[XD];
    sv[t] = wV[(size_t)i*XD + t];
    __syncthreads();
    const float4* W4 = (const float4*)(Wxo + (size_t)t*XD);
    const float4* v4 = (const float4*)sv;
    float acc = 0.f;
    #pragma unroll 8
    for (int k4 = 0; k4 < XD/4; ++k4) {
        float4 w = W4[k4]; float4 v = v4[k4];
        acc += w.x*v.x + w.y*v.y + w.z*v.z + w.w*v.w;
    }
    outX[(size_t)i*XD + t] = acc + bxo[t];
}

extern "C" void kernel_launch(void* const* d_in, const int* in_sizes, int n_in,
                              void* d_out, int out_size, void* d_ws, size_t ws_size,
                              hipStream_t stream) {
    const float* x   = (const float*)d_in[0];
    const float* e   = (const float*)d_in[1];
    // d_in[2] = adj (unused by reference)
    const float* Wq  = (const float*)d_in[3];
    const float* bq  = (const float*)d_in[4];
    const float* Wk  = (const float*)d_in[5];
    const float* bk  = (const float*)d_in[6];
    const float* Wv  = (const float*)d_in[7];
    const float* bv  = (const float*)d_in[8];
    const float* Wem = (const float*)d_in[9];
    const float* bem = (const float*)d_in[10];
    const float* Wea = (const float*)d_in[11];
    const float* bea = (const float*)d_in[12];
    const float* Wxo = (const float*)d_in[13];
    const float* bxo = (const float*)d_in[14];
    const float* Weo = (const float*)d_in[15];
    const float* beo = (const float*)d_in[16];

    float* ws  = (float*)d_ws;
    float* Qs  = ws;                 // [512][256] pre-scaled Q
    float* Km  = ws + (size_t)NN*XD;       // [512][256]
    float* Vm  = ws + (size_t)2*NN*XD;     // [512][256]
    float* wVv = ws + (size_t)3*NN*XD;     // [512][256] weighted V

    float* outX = (float*)d_out;               // [512][256]
    float* outE = outX + (size_t)NN*XD;        // [512][512][128]

    qkv_kernel<<<dim3(NN, 3), 256, 0, stream>>>(x, Wq, bq, Wk, bk, Wv, bv, ws);
    fused_kernel<<<NN, 512, 0, stream>>>(e, Qs, Km, Vm, Wem, bem, Wea, bea,
                                         Weo, beo, outE, wVv);
    newx_kernel<<<NN, 256, 0, stream>>>(wVv, Wxo, bxo, outX);
}

// Round 2
// 539.118 us; speedup vs baseline: 1.0314x; 1.0314x over previous
//
#include <hip/hip_runtime.h>
#include <math.h>

#define NN 512
#define XD 256
#define ED 128
#define JC 32
#define NCHUNK (NN/JC)

typedef __attribute__((ext_vector_type(8))) short s8v;
typedef __attribute__((ext_vector_type(4))) float f4v;

__device__ __forceinline__ short f2bf(float f) {
    union { float f; unsigned u; } v; v.f = f;
    unsigned r = (v.u + 0x7FFFu + ((v.u >> 16) & 1u)) >> 16;
    return (short)r;
}
__device__ __forceinline__ s8v load8_bf(const float* __restrict__ p) {
    const float4* p4 = (const float4*)p;
    float4 a = p4[0], b = p4[1];
    s8v r;
    r[0]=f2bf(a.x); r[1]=f2bf(a.y); r[2]=f2bf(a.z); r[3]=f2bf(a.w);
    r[4]=f2bf(b.x); r[5]=f2bf(b.y); r[6]=f2bf(b.z); r[7]=f2bf(b.w);
    return r;
}
__device__ __forceinline__ float bf2f(short s) {
    union { unsigned u; float f; } v;
    v.u = ((unsigned)(unsigned short)s) << 16;
    return v.f;
}

// ---------------- kernel 0: weights -> bf16 (once, cheap) ----------------
__global__ void wconv_kernel(const float* __restrict__ Wem, const float* __restrict__ Wea,
                             const float* __restrict__ Weo,
                             short* __restrict__ Wem_bf, short* __restrict__ Wea_bf,
                             short* __restrict__ Weo_bf) {
    const float* src; short* dst;
    if (blockIdx.y == 0)      { src = Wem; dst = Wem_bf; }
    else if (blockIdx.y == 1) { src = Wea; dst = Wea_bf; }
    else                      { src = Weo; dst = Weo_bf; }
    const int off = (blockIdx.x * 256 + threadIdx.x) * 8;   // 16 blocks * 256 thr * 8 = 32768
    *(s8v*)(dst + off) = load8_bf(src + off);
}

// ---------------- kernel 1: Q (pre-scaled), K, V ----------------
__global__ void qkv_kernel(const float* __restrict__ x,
                           const float* __restrict__ Wq, const float* __restrict__ bq,
                           const float* __restrict__ Wk, const float* __restrict__ bk,
                           const float* __restrict__ Wv, const float* __restrict__ bv,
                           float* __restrict__ out) {
    const int i = blockIdx.x, which = blockIdx.y, t = threadIdx.x;
    __shared__ float sx[XD];
    sx[t] = x[i*XD + t];
    __syncthreads();
    const float* W = which==0 ? Wq : (which==1 ? Wk : Wv);
    const float* b = which==0 ? bq : (which==1 ? bk : bv);
    const float4* W4 = (const float4*)(W + (size_t)t*XD);
    const float4* x4 = (const float4*)sx;
    float acc = 0.f;
    #pragma unroll 8
    for (int k4 = 0; k4 < XD/4; ++k4) {
        float4 w = W4[k4]; float4 xv = x4[k4];
        acc += w.x*xv.x + w.y*xv.y + w.z*xv.z + w.w*xv.w;
    }
    acc += b[t];
    if (which == 0) acc *= 0.17677669529663688f;  // 1/sqrt(32)
    out[((size_t)which*NN + i)*XD + t] = acc;
}

// ---------------- kernel 2: pass 1 — one (i, j-chunk) per block ----------------
#define SE_STRIDE 136   // 128 + 8 pad (bf16 units)
#define SY_STRIDE 264   // 256 + 8 pad

__global__ __launch_bounds__(512, 2) void pass1_kernel(
    const float* __restrict__ e,
    const float* __restrict__ Qs, const float* __restrict__ Km, const float* __restrict__ Vm,
    const short* __restrict__ Wem_bf, const float* __restrict__ bem,
    const short* __restrict__ Wea_bf, const float* __restrict__ bea,
    const short* __restrict__ Weo_bf, const float* __restrict__ beo,
    float* __restrict__ outE,
    float* __restrict__ Pm, float* __restrict__ Pl, float* __restrict__ Pa)
{
    __shared__ short sE[JC*SE_STRIDE];
    __shared__ short sY[JC*SY_STRIDE];
    __shared__ float sRed[3*512];

    const int ch = blockIdx.x;
    const int i  = blockIdx.y;
    const int t = threadIdx.x;
    const int wave = t >> 6;
    const int lane = t & 63;
    const int quad = (lane >> 4) & 3;
    const int l16 = lane & 15;

    // --- B fragments: plain bf16 loads (pre-converted) ---
    const int wn0 = wave * 32;
    s8v B1f[2][4], B2f[2][4];
    float q_l[2], bm1[2], bea_l[2];
    #pragma unroll
    for (int nt = 0; nt < 2; ++nt) {
        const int c = wn0 + nt*16 + l16;
        q_l[nt]   = Qs[i*XD + c];
        bm1[nt]   = bem[c] + 1.0f;
        bea_l[nt] = bea[c];
        #pragma unroll
        for (int ks = 0; ks < 4; ++ks) {
            const int kb = ks*32 + quad*8;
            B1f[nt][ks] = *(const s8v*)(Wem_bf + (size_t)c*ED + kb);
            B2f[nt][ks] = *(const s8v*)(Wea_bf + (size_t)c*ED + kb);
        }
    }
    const int oo = wave*16 + l16;
    s8v B3f[8];
    #pragma unroll
    for (int ks = 0; ks < 8; ++ks)
        B3f[ks] = *(const s8v*)(Weo_bf + (size_t)oo*XD + ks*32 + quad*8);
    const float beo_l = beo[oo];

    // --- stage e chunk -> LDS bf16 ---
    {
        const int j  = t >> 4;
        const int k0 = (t & 15) * 8;
        const float* src = e + ((size_t)i*NN + (size_t)(ch*JC + j))*ED + k0;
        *(s8v*)(&sE[j*SE_STRIDE + k0]) = load8_bf(src);
    }
    __syncthreads();

    // --- GEMM1/2: E1,E2 [32 x 256] ---
    f4v acc1[2][2], acc2[2][2];
    #pragma unroll
    for (int mt = 0; mt < 2; ++mt)
        #pragma unroll
        for (int nt = 0; nt < 2; ++nt) {
            f4v z = {0.f, 0.f, 0.f, 0.f};
            acc1[mt][nt] = z; acc2[mt][nt] = z;
        }
    #pragma unroll
    for (int ks = 0; ks < 4; ++ks) {
        #pragma unroll
        for (int mt = 0; mt < 2; ++mt) {
            s8v af = *(const s8v*)(&sE[(mt*16 + l16)*SE_STRIDE + ks*32 + quad*8]);
            #pragma unroll
            for (int nt = 0; nt < 2; ++nt) {
                acc1[mt][nt] = __builtin_amdgcn_mfma_f32_16x16x32_bf16(af, B1f[nt][ks], acc1[mt][nt], 0, 0, 0);
                acc2[mt][nt] = __builtin_amdgcn_mfma_f32_16x16x32_bf16(af, B2f[nt][ks], acc2[mt][nt], 0, 0, 0);
            }
        }
    }

    // --- elementwise: Y = qK*(E1+1) + E2  -> sY (bf16) ---
    #pragma unroll
    for (int mt = 0; mt < 2; ++mt) {
        const int jlb = mt*16 + quad*4;
        const int jgb = ch*JC + jlb;
        #pragma unroll
        for (int nt = 0; nt < 2; ++nt) {
            const int c = wn0 + nt*16 + l16;
            #pragma unroll
            for (int r = 0; r < 4; ++r) {
                float e1 = acc1[mt][nt][r] + bm1[nt];
                float e2 = acc2[mt][nt][r] + bea_l[nt];
                float kv = Km[(size_t)(jgb + r)*XD + c];
                float y  = q_l[nt]*kv*e1 + e2;
                sY[(jlb + r)*SY_STRIDE + c] = f2bf(y);
            }
        }
    }
    __syncthreads();

    // --- GEMM3: newE chunk [32 x 128] ---
    f4v acc3[2];
    {
        f4v z = {0.f, 0.f, 0.f, 0.f};
        acc3[0] = z; acc3[1] = z;
    }
    #pragma unroll
    for (int ks = 0; ks < 8; ++ks)
        #pragma unroll
        for (int mt = 0; mt < 2; ++mt) {
            s8v af = *(const s8v*)(&sY[(mt*16 + l16)*SY_STRIDE + ks*32 + quad*8]);
            acc3[mt] = __builtin_amdgcn_mfma_f32_16x16x32_bf16(af, B3f[ks], acc3[mt], 0, 0, 0);
        }
    #pragma unroll
    for (int mt = 0; mt < 2; ++mt) {
        const int jlb = mt*16 + quad*4;
        #pragma unroll
        for (int r = 0; r < 4; ++r) {
            const int jg = ch*JC + jlb + r;
            outE[((size_t)i*NN + jg)*ED + oo] = acc3[mt][r] + beo_l;
        }
    }

    // --- partial softmax over this chunk's 32 j's ---
    const int sc_c  = t & 255;
    const int sc_jh = t >> 8;
    float m_run = -INFINITY, l_run = 0.f, a_run = 0.f;
    #pragma unroll
    for (int jj = 0; jj < 16; ++jj) {
        const int jl = sc_jh*16 + jj;
        const int jg = ch*JC + jl;
        float y  = bf2f(sY[jl*SY_STRIDE + sc_c]);
        float v  = Vm[(size_t)jg*XD + sc_c];
        float mn = fmaxf(m_run, y);
        float s0 = __expf(m_run - mn);
        float p  = __expf(y - mn);
        l_run = l_run*s0 + p;
        a_run = a_run*s0 + p*v;
        m_run = mn;
    }
    __syncthreads();
    sRed[t] = m_run; sRed[512 + t] = l_run; sRed[1024 + t] = a_run;
    __syncthreads();
    if (t < 256) {
        float m0 = sRed[t],        m1 = sRed[256 + t];
        float l0 = sRed[512 + t],  l1 = sRed[768 + t];
        float a0 = sRed[1024 + t], a1 = sRed[1280 + t];
        float M  = fmaxf(m0, m1);
        float e0 = __expf(m0 - M), e1x = __expf(m1 - M);
        const size_t pb = ((size_t)i*NCHUNK + ch)*256 + t;
        Pm[pb] = M;
        Pl[pb] = l0*e0 + l1*e1x;
        Pa[pb] = a0*e0 + a1*e1x;
    }
}

// ---------------- kernel 3: pass 2 — combine partials + newX ----------------
__global__ void pass2_kernel(const float* __restrict__ Pm, const float* __restrict__ Pl,
                             const float* __restrict__ Pa,
                             const float* __restrict__ Wxo, const float* __restrict__ bxo,
                             float* __restrict__ outX) {
    const int i = blockIdx.x, t = threadIdx.x;
    float mloc[NCHUNK];
    float M = -INFINITY;
    #pragma unroll
    for (int ch = 0; ch < NCHUNK; ++ch) {
        mloc[ch] = Pm[((size_t)i*NCHUNK + ch)*256 + t];
        M = fmaxf(M, mloc[ch]);
    }
    float L = 0.f, A = 0.f;
    #pragma unroll
    for (int ch = 0; ch < NCHUNK; ++ch) {
        const size_t pb = ((size_t)i*NCHUNK + ch)*256 + t;
        float s = __expf(mloc[ch] - M);
        L += Pl[pb]*s;
        A += Pa[pb]*s;
    }
    __shared__ float sv[XD];
    sv[t] = A / L;
    __syncthreads();
    const float4* W4 = (const float4*)(Wxo + (size_t)t*XD);
    const float4* v4 = (const float4*)sv;
    float acc = 0.f;
    #pragma unroll 8
    for (int k4 = 0; k4 < XD/4; ++k4) {
        float4 w = W4[k4]; float4 v = v4[k4];
        acc += w.x*v.x + w.y*v.y + w.z*v.z + w.w*v.w;
    }
    outX[(size_t)i*XD + t] = acc + bxo[t];
}

extern "C" void kernel_launch(void* const* d_in, const int* in_sizes, int n_in,
                              void* d_out, int out_size, void* d_ws, size_t ws_size,
                              hipStream_t stream) {
    const float* x   = (const float*)d_in[0];
    const float* e   = (const float*)d_in[1];
    // d_in[2] = adj (unused by reference)
    const float* Wq  = (const float*)d_in[3];
    const float* bq  = (const float*)d_in[4];
    const float* Wk  = (const float*)d_in[5];
    const float* bk  = (const float*)d_in[6];
    const float* Wv  = (const float*)d_in[7];
    const float* bv  = (const float*)d_in[8];
    const float* Wem = (const float*)d_in[9];
    const float* bem = (const float*)d_in[10];
    const float* Wea = (const float*)d_in[11];
    const float* bea = (const float*)d_in[12];
    const float* Wxo = (const float*)d_in[13];
    const float* bxo = (const float*)d_in[14];
    const float* Weo = (const float*)d_in[15];
    const float* beo = (const float*)d_in[16];

    float* ws = (float*)d_ws;
    float* Qs = ws;                              // [512][256] pre-scaled Q
    float* Km = ws + (size_t)NN*XD;              // [512][256]
    float* Vm = ws + (size_t)2*NN*XD;            // [512][256]
    float* Pm = ws + (size_t)3*NN*XD;            // [512][16][256]
    float* Pl = Pm + (size_t)NN*NCHUNK*XD;
    float* Pa = Pl + (size_t)NN*NCHUNK*XD;
    short* Wem_bf = (short*)(Pa + (size_t)NN*NCHUNK*XD);   // [256][128] bf16
    short* Wea_bf = Wem_bf + (size_t)XD*ED;
    short* Weo_bf = Wea_bf + (size_t)XD*ED;                // [128][256] bf16

    float* outX = (float*)d_out;                 // [512][256]
    float* outE = outX + (size_t)NN*XD;          // [512][512][128]

    wconv_kernel<<<dim3(16, 3), 256, 0, stream>>>(Wem, Wea, Weo, Wem_bf, Wea_bf, Weo_bf);
    qkv_kernel<<<dim3(NN, 3), 256, 0, stream>>>(x, Wq, bq, Wk, bk, Wv, bv, ws);
    pass1_kernel<<<dim3(NCHUNK, NN), 512, 0, stream>>>(e, Qs, Km, Vm,
                                                       Wem_bf, bem, Wea_bf, bea,
                                                       Weo_bf, beo, outE, Pm, Pl, Pa);
    pass2_kernel<<<NN, 256, 0, stream>>>(Pm, Pl, Pa, Wxo, bxo, outX);
}

// Round 3
// 389.777 us; speedup vs baseline: 1.4266x; 1.3831x over previous
//
#include <hip/hip_runtime.h>
#include <math.h>

#define NN 512
#define XD 256
#define ED 128
#define JC 32
#define NCHUNK (NN/JC)

typedef __attribute__((ext_vector_type(8))) short s8v;
typedef __attribute__((ext_vector_type(4))) float f4v;

__device__ __forceinline__ short f2bf(float f) {
    union { float f; unsigned u; } v; v.f = f;
    unsigned r = (v.u + 0x7FFFu + ((v.u >> 16) & 1u)) >> 16;
    return (short)r;
}
__device__ __forceinline__ s8v load8_bf(const float* __restrict__ p) {
    const float4* p4 = (const float4*)p;
    float4 a = p4[0], b = p4[1];
    s8v r;
    r[0]=f2bf(a.x); r[1]=f2bf(a.y); r[2]=f2bf(a.z); r[3]=f2bf(a.w);
    r[4]=f2bf(b.x); r[5]=f2bf(b.y); r[6]=f2bf(b.z); r[7]=f2bf(b.w);
    return r;
}
__device__ __forceinline__ float bf2f(short s) {
    union { unsigned u; float f; } v;
    v.u = ((unsigned)(unsigned short)s) << 16;
    return v.f;
}

// ---------------- kernel 0: weights -> bf16 in MFMA-fragment order ----------------
// GEMM1/2 B-frag layout (Wem/Wea, W[c][k], 256x128):
//   frag f = (cb*4 + ks)*64 + quad*16 + l16  -> 8 shorts from W[cb*16+l16][ks*32+quad*8 ..]
// GEMM3 B-frag layout (Weo, W[oo][k], 128x256):
//   frag f = (ob*8 + ks)*64 + quad*16 + l16  -> 8 shorts from W[ob*16+l16][ks*32+quad*8 ..]
__global__ void wconv_kernel(const float* __restrict__ Wem, const float* __restrict__ Wea,
                             const float* __restrict__ Weo,
                             short* __restrict__ Wem_bf, short* __restrict__ Wea_bf,
                             short* __restrict__ Weo_bf) {
    const int f = blockIdx.x * 256 + threadIdx.x;   // [0, 4096)
    const int lane = f & 63;
    const int quad = lane >> 4;
    const int l16  = lane & 15;
    if (blockIdx.y < 2) {
        const float* src = blockIdx.y == 0 ? Wem : Wea;
        short* dst = blockIdx.y == 0 ? Wem_bf : Wea_bf;
        const int cb = f >> 8;
        const int ks = (f >> 6) & 3;
        *(s8v*)(dst + (size_t)f * 8) =
            load8_bf(src + (size_t)(cb*16 + l16)*ED + ks*32 + quad*8);
    } else {
        const int ob = f >> 9;
        const int ks = (f >> 6) & 7;
        *(s8v*)(Weo_bf + (size_t)f * 8) =
            load8_bf(Weo + (size_t)(ob*16 + l16)*XD + ks*32 + quad*8);
    }
}

// ---------------- kernel 1: Q (pre-scaled), K, V ----------------
__global__ void qkv_kernel(const float* __restrict__ x,
                           const float* __restrict__ Wq, const float* __restrict__ bq,
                           const float* __restrict__ Wk, const float* __restrict__ bk,
                           const float* __restrict__ Wv, const float* __restrict__ bv,
                           float* __restrict__ out) {
    const int i = blockIdx.x, which = blockIdx.y, t = threadIdx.x;
    __shared__ float sx[XD];
    sx[t] = x[i*XD + t];
    __syncthreads();
    const float* W = which==0 ? Wq : (which==1 ? Wk : Wv);
    const float* b = which==0 ? bq : (which==1 ? bk : bv);
    const float4* W4 = (const float4*)(W + (size_t)t*XD);
    const float4* x4 = (const float4*)sx;
    float acc = 0.f;
    #pragma unroll 8
    for (int k4 = 0; k4 < XD/4; ++k4) {
        float4 w = W4[k4]; float4 xv = x4[k4];
        acc += w.x*xv.x + w.y*xv.y + w.z*xv.z + w.w*xv.w;
    }
    acc += b[t];
    if (which == 0) acc *= 0.17677669529663688f;  // 1/sqrt(32)
    out[((size_t)which*NN + i)*XD + t] = acc;
}

// ---------------- kernel 2: pass 1 — one (i, j-chunk) per block ----------------
#define SE_STRIDE 136   // 128 + 8 pad (bf16 units)
#define SY_STRIDE 264   // 256 + 8 pad

__global__ __launch_bounds__(512, 4) void pass1_kernel(
    const float* __restrict__ e,
    const float* __restrict__ Qs, const float* __restrict__ Km, const float* __restrict__ Vm,
    const short* __restrict__ Wem_bf, const float* __restrict__ bem,
    const short* __restrict__ Wea_bf, const float* __restrict__ bea,
    const short* __restrict__ Weo_bf, const float* __restrict__ beo,
    float* __restrict__ outE,
    float* __restrict__ Pm, float* __restrict__ Pl, float* __restrict__ Pa)
{
    __shared__ short sE[JC*SE_STRIDE];   // 8704 B; reused as reduction buffer at the end
    __shared__ short sY[JC*SY_STRIDE];   // 16896 B

    const int ch = blockIdx.x;
    const int i  = blockIdx.y;
    const int t = threadIdx.x;
    const int wave = t >> 6;
    const int lane = t & 63;
    const int quad = (lane >> 4) & 3;
    const int l16 = lane & 15;

    const int wn0 = wave * 32;
    float q_l[2], bm1[2], bea_l[2];
    #pragma unroll
    for (int nt = 0; nt < 2; ++nt) {
        const int c = wn0 + nt*16 + l16;
        q_l[nt]   = Qs[i*XD + c];
        bm1[nt]   = bem[c] + 1.0f;
        bea_l[nt] = bea[c];
    }
    const int oo = wave*16 + l16;
    const float beo_l = beo[oo];

    // fragment-ordered weight pointers (coalesced: 16 B per lane)
    const s8v* W1p = (const s8v*)(Wem_bf + ((size_t)wave*8*64 + lane)*8);
    const s8v* W2p = (const s8v*)(Wea_bf + ((size_t)wave*8*64 + lane)*8);
    const s8v* W3p = (const s8v*)(Weo_bf + ((size_t)wave*8*64 + lane)*8);

    // --- stage e chunk -> LDS bf16 ---
    {
        const int j  = t >> 4;
        const int k0 = (t & 15) * 8;
        const float* src = e + ((size_t)i*NN + (size_t)(ch*JC + j))*ED + k0;
        *(s8v*)(&sE[j*SE_STRIDE + k0]) = load8_bf(src);
    }
    __syncthreads();

    // --- GEMM1/2: E1,E2 [32 x 256], B-frags streamed from L2 ---
    f4v acc1[2][2], acc2[2][2];
    #pragma unroll
    for (int mt = 0; mt < 2; ++mt)
        #pragma unroll
        for (int nt = 0; nt < 2; ++nt) {
            f4v z = {0.f, 0.f, 0.f, 0.f};
            acc1[mt][nt] = z; acc2[mt][nt] = z;
        }
    #pragma unroll
    for (int ks = 0; ks < 4; ++ks) {
        s8v a0 = *(const s8v*)(&sE[(     l16)*SE_STRIDE + ks*32 + quad*8]);
        s8v a1 = *(const s8v*)(&sE[(16 + l16)*SE_STRIDE + ks*32 + quad*8]);
        #pragma unroll
        for (int nt = 0; nt < 2; ++nt) {
            s8v b1 = W1p[(nt*4 + ks)*64];
            s8v b2 = W2p[(nt*4 + ks)*64];
            acc1[0][nt] = __builtin_amdgcn_mfma_f32_16x16x32_bf16(a0, b1, acc1[0][nt], 0, 0, 0);
            acc1[1][nt] = __builtin_amdgcn_mfma_f32_16x16x32_bf16(a1, b1, acc1[1][nt], 0, 0, 0);
            acc2[0][nt] = __builtin_amdgcn_mfma_f32_16x16x32_bf16(a0, b2, acc2[0][nt], 0, 0, 0);
            acc2[1][nt] = __builtin_amdgcn_mfma_f32_16x16x32_bf16(a1, b2, acc2[1][nt], 0, 0, 0);
        }
    }

    // --- elementwise: Y = qK*(E1+1) + E2  -> sY (bf16) ---
    #pragma unroll
    for (int mt = 0; mt < 2; ++mt) {
        const int jlb = mt*16 + quad*4;
        const int jgb = ch*JC + jlb;
        #pragma unroll
        for (int nt = 0; nt < 2; ++nt) {
            const int c = wn0 + nt*16 + l16;
            #pragma unroll
            for (int r = 0; r < 4; ++r) {
                float e1 = acc1[mt][nt][r] + bm1[nt];
                float e2 = acc2[mt][nt][r] + bea_l[nt];
                float kv = Km[(size_t)(jgb + r)*XD + c];
                float y  = q_l[nt]*kv*e1 + e2;
                sY[(jlb + r)*SY_STRIDE + c] = f2bf(y);
            }
        }
    }
    __syncthreads();

    // --- GEMM3: newE chunk [32 x 128], B-frags streamed ---
    f4v acc3[2];
    {
        f4v z = {0.f, 0.f, 0.f, 0.f};
        acc3[0] = z; acc3[1] = z;
    }
    #pragma unroll
    for (int ks = 0; ks < 8; ++ks) {
        s8v b3 = W3p[ks*64];
        s8v a0 = *(const s8v*)(&sY[(     l16)*SY_STRIDE + ks*32 + quad*8]);
        s8v a1 = *(const s8v*)(&sY[(16 + l16)*SY_STRIDE + ks*32 + quad*8]);
        acc3[0] = __builtin_amdgcn_mfma_f32_16x16x32_bf16(a0, b3, acc3[0], 0, 0, 0);
        acc3[1] = __builtin_amdgcn_mfma_f32_16x16x32_bf16(a1, b3, acc3[1], 0, 0, 0);
    }
    #pragma unroll
    for (int mt = 0; mt < 2; ++mt) {
        const int jlb = mt*16 + quad*4;
        #pragma unroll
        for (int r = 0; r < 4; ++r) {
            const int jg = ch*JC + jlb + r;
            outE[((size_t)i*NN + jg)*ED + oo] = acc3[mt][r] + beo_l;
        }
    }

    // --- partial softmax over this chunk's 32 j's ---
    const int sc_c  = t & 255;
    const int sc_jh = t >> 8;
    float m_run = -INFINITY, l_run = 0.f, a_run = 0.f;
    #pragma unroll
    for (int jj = 0; jj < 16; ++jj) {
        const int jl = sc_jh*16 + jj;
        const int jg = ch*JC + jl;
        float y  = bf2f(sY[jl*SY_STRIDE + sc_c]);
        float v  = Vm[(size_t)jg*XD + sc_c];
        float mn = fmaxf(m_run, y);
        float s0 = __expf(m_run - mn);
        float p  = __expf(y - mn);
        l_run = l_run*s0 + p;
        a_run = a_run*s0 + p*v;
        m_run = mn;
    }
    __syncthreads();
    // reduction buffer aliases sE (all waves are past their last sE read here)
    float* sRed = (float*)sE;
    float* sRed2 = (float*)sY;   // use sY space for the other two arrays
    sRed[t] = m_run; sRed2[t] = l_run; sRed2[512 + t] = a_run;
    __syncthreads();
    if (t < 256) {
        float m0 = sRed[t],       m1 = sRed[256 + t];
        float l0 = sRed2[t],      l1 = sRed2[256 + t];
        float a0 = sRed2[512+t],  a1 = sRed2[768 + t];
        float M  = fmaxf(m0, m1);
        float e0 = __expf(m0 - M), e1x = __expf(m1 - M);
        const size_t pb = ((size_t)i*NCHUNK + ch)*256 + t;
        Pm[pb] = M;
        Pl[pb] = l0*e0 + l1*e1x;
        Pa[pb] = a0*e0 + a1*e1x;
    }
}

// ---------------- kernel 3: pass 2 — combine partials + newX ----------------
__global__ void pass2_kernel(const float* __restrict__ Pm, const float* __restrict__ Pl,
                             const float* __restrict__ Pa,
                             const float* __restrict__ Wxo, const float* __restrict__ bxo,
                             float* __restrict__ outX) {
    const int i = blockIdx.x, t = threadIdx.x;
    float mloc[NCHUNK];
    float M = -INFINITY;
    #pragma unroll
    for (int ch = 0; ch < NCHUNK; ++ch) {
        mloc[ch] = Pm[((size_t)i*NCHUNK + ch)*256 + t];
        M = fmaxf(M, mloc[ch]);
    }
    float L = 0.f, A = 0.f;
    #pragma unroll
    for (int ch = 0; ch < NCHUNK; ++ch) {
        const size_t pb = ((size_t)i*NCHUNK + ch)*256 + t;
        float s = __expf(mloc[ch] - M);
        L += Pl[pb]*s;
        A += Pa[pb]*s;
    }
    __shared__ float sv[XD];
    sv[t] = A / L;
    __syncthreads();
    const float4* W4 = (const float4*)(Wxo + (size_t)t*XD);
    const float4* v4 = (const float4*)sv;
    float acc = 0.f;
    #pragma unroll 8
    for (int k4 = 0; k4 < XD/4; ++k4) {
        float4 w = W4[k4]; float4 v = v4[k4];
        acc += w.x*v.x + w.y*v.y + w.z*v.z + w.w*v.w;
    }
    outX[(size_t)i*XD + t] = acc + bxo[t];
}

extern "C" void kernel_launch(void* const* d_in, const int* in_sizes, int n_in,
                              void* d_out, int out_size, void* d_ws, size_t ws_size,
                              hipStream_t stream) {
    const float* x   = (const float*)d_in[0];
    const float* e   = (const float*)d_in[1];
    // d_in[2] = adj (unused by reference)
    const float* Wq  = (const float*)d_in[3];
    const float* bq  = (const float*)d_in[4];
    const float* Wk  = (const float*)d_in[5];
    const float* bk  = (const float*)d_in[6];
    const float* Wv  = (const float*)d_in[7];
    const float* bv  = (const float*)d_in[8];
    const float* Wem = (const float*)d_in[9];
    const float* bem = (const float*)d_in[10];
    const float* Wea = (const float*)d_in[11];
    const float* bea = (const float*)d_in[12];
    const float* Wxo = (const float*)d_in[13];
    const float* bxo = (const float*)d_in[14];
    const float* Weo = (const float*)d_in[15];
    const float* beo = (const float*)d_in[16];

    float* ws = (float*)d_ws;
    float* Qs = ws;                              // [512][256] pre-scaled Q
    float* Km = ws + (size_t)NN*XD;              // [512][256]
    float* Vm = ws + (size_t)2*NN*XD;            // [512][256]
    float* Pm = ws + (size_t)3*NN*XD;            // [512][16][256]
    float* Pl = Pm + (size_t)NN*NCHUNK*XD;
    float* Pa = Pl + (size_t)NN*NCHUNK*XD;
    short* Wem_bf = (short*)(Pa + (size_t)NN*NCHUNK*XD);   // fragment-ordered bf16
    short* Wea_bf = Wem_bf + (size_t)XD*ED;
    short* Weo_bf = Wea_bf + (size_t)XD*ED;

    float* outX = (float*)d_out;                 // [512][256]
    float* outE = outX + (size_t)NN*XD;          // [512][512][128]

    wconv_kernel<<<dim3(16, 3), 256, 0, stream>>>(Wem, Wea, Weo, Wem_bf, Wea_bf, Weo_bf);
    qkv_kernel<<<dim3(NN, 3), 256, 0, stream>>>(x, Wq, bq, Wk, bk, Wv, bv, ws);
    pass1_kernel<<<dim3(NCHUNK, NN), 512, 0, stream>>>(e, Qs, Km, Vm,
                                                       Wem_bf, bem, Wea_bf, bea,
                                                       Weo_bf, beo, outE, Pm, Pl, Pa);
    pass2_kernel<<<NN, 256, 0, stream>>>(Pm, Pl, Pa, Wxo, bxo, outX);
}